// Round 1
// baseline (187.562 us; speedup 1.0000x reference)
//
#include <hip/hip_runtime.h>

#define B_   4
#define H_   64
#define W_   64
#define C_   256
#define HO_  58
#define WO_  58
#define R_   3
#define NKEY 48   // 49 cells minus the center

__global__ __launch_bounds__(256) void convnd_attn_kernel(const float* __restrict__ X,
                                                          float* __restrict__ out) {
    __shared__ float keybuf[NKEY * C_];  // 48 KiB: staged keys (also values)
    __shared__ float sw[NKEY];           // scores, then softmax weights

    const int blk = blockIdx.x;
    const int j   = blk % WO_;
    const int t1  = blk / WO_;
    const int i   = t1 % HO_;
    const int b   = t1 / HO_;

    const int tid  = threadIdx.x;   // 0..255
    const int wave = tid >> 6;      // 0..3
    const int lane = tid & 63;      // 0..63

    const float* base = X + (size_t)(b * H_) * W_ * C_;

    // q = window center (i+3, j+3); lane holds channels 4*lane..4*lane+3
    const float* qp = base + ((i + R_) * W_ + (j + R_)) * C_;
    const float4 qv = *(const float4*)(qp + 4 * lane);

    // Phase 1: each wave computes 12 key dot-products, stages keys to LDS.
    #pragma unroll
    for (int kk = 0; kk < 12; ++kk) {
        const int k    = wave * 12 + kk;
        const int cell = k + (k >= 24 ? 1 : 0);   // skip center cell 24
        const int di   = cell / 7;
        const int dj   = cell % 7;
        const float* kp = base + ((i + di) * W_ + (j + dj)) * C_;
        const float4 kv = *(const float4*)(kp + 4 * lane);
        ((float4*)(keybuf + k * C_))[lane] = kv;
        float p = qv.x * kv.x + qv.y * kv.y + qv.z * kv.z + qv.w * kv.w;
        #pragma unroll
        for (int off = 32; off; off >>= 1) p += __shfl_xor(p, off, 64);
        if (lane == 0) sw[k] = p * 0.0625f;       // / sqrt(256)
    }
    __syncthreads();

    // Phase 2: softmax over 48 scores, done by wave 0.
    if (wave == 0) {
        const float s = (lane < NKEY) ? sw[lane] : -3.0e38f;
        float m = s;
        #pragma unroll
        for (int off = 32; off; off >>= 1) m = fmaxf(m, __shfl_xor(m, off, 64));
        float e = (lane < NKEY) ? __expf(s - m) : 0.0f;
        float t = e;
        #pragma unroll
        for (int off = 32; off; off >>= 1) t += __shfl_xor(t, off, 64);
        if (lane < NKEY) sw[lane] = e / t;
    }
    __syncthreads();

    // Phase 3: thread c = tid accumulates the weighted value sum for its channel.
    float acc = 0.0f;
    #pragma unroll
    for (int k = 0; k < NKEY; ++k)
        acc = fmaf(sw[k], keybuf[k * C_ + tid], acc);

    out[((b * HO_ + i) * WO_ + j) * C_ + tid] = acc;
}

extern "C" void kernel_launch(void* const* d_in, const int* in_sizes, int n_in,
                              void* d_out, int out_size, void* d_ws, size_t ws_size,
                              hipStream_t stream) {
    const float* X = (const float*)d_in[0];
    float* out    = (float*)d_out;
    hipLaunchKernelGGL(convnd_attn_kernel,
                       dim3(B_ * HO_ * WO_), dim3(256), 0, stream, X, out);
}